// Round 3
// baseline (602.021 us; speedup 1.0000x reference)
//
#include <hip/hip_runtime.h>
#include <math.h>

static constexpr int NCLS = 80;
#define FG_T 0.5f
#define BG_T 0.4f
#define BETA_C 0.1f

// ---- bit-stable IoU helpers (no FMA contraction so that both passes and
// ---- the NumPy reference produce bit-identical float32 values) ----
__device__ __forceinline__ float box_area_nc(float x1, float y1, float x2, float y2) {
#pragma clang fp contract(off)
  return (x2 - x1) * (y2 - y1);
}

__device__ __forceinline__ float iou_nc(float ax1, float ay1, float ax2, float ay2, float aarea,
                                        float gx1, float gy1, float gx2, float gy2, float garea) {
#pragma clang fp contract(off)
  float lx = fmaxf(ax1, gx1);
  float ly = fmaxf(ay1, gy1);
  float rx = fminf(ax2, gx2);
  float ry = fminf(ay2, gy2);
  float w = fmaxf(rx - lx, 0.0f);
  float h = fmaxf(ry - ly, 0.0f);
  float inter = w * h;
  return inter / (aarea + garea - inter);
}

// ---- kernel 0: zero accumulators + per-gt max array ----
__global__ void k_init(double* acc, unsigned int* maxpg, int n) {
  int i = blockIdx.x * blockDim.x + threadIdx.x;
  if (i < 4) acc[i] = 0.0;
  if (i < n) maxpg[i] = 0u;
}

// ---- kernel 1: max IoU per gt (lane = gt index, one wave per anchor chunk) ----
__global__ __launch_bounds__(256) void k_maxpg(const float* __restrict__ anchors,
                                               const float* __restrict__ gt_boxes,
                                               unsigned int* __restrict__ maxpg,
                                               int R, int G, int CH) {
  const int lane = threadIdx.x & 63;
  const int wid = blockIdx.x * (blockDim.x >> 6) + (threadIdx.x >> 6);
  const int b = blockIdx.y;
  const int r0 = wid * CH;
  if (r0 >= R) return;
  float gx1 = 0.f, gy1 = 0.f, gx2 = 0.f, gy2 = 0.f, garea = 0.f;
  if (lane < G) {
    const float4 gb = *(const float4*)(gt_boxes + ((size_t)b * G + lane) * 4);
    gx1 = gb.x; gy1 = gb.y; gx2 = gb.z; gy2 = gb.w;
    garea = box_area_nc(gx1, gy1, gx2, gy2);
  }
  float m = 0.0f;
  const int r1 = min(r0 + CH, R);
  for (int r = r0; r < r1; ++r) {
    const float4 a = *(const float4*)(anchors + (size_t)r * 4);
    const float aarea = box_area_nc(a.x, a.y, a.z, a.w);
    const float iou = iou_nc(a.x, a.y, a.z, a.w, aarea, gx1, gy1, gx2, gy2, garea);
    m = fmaxf(m, iou);
  }
  if (lane < G) atomicMax(&maxpg[b * G + lane], __float_as_uint(m));  // iou >= 0
}

// ---- kernel 2: per-anchor assignment + smooth L1 + fg count ----
__global__ __launch_bounds__(256) void k_assign(const float* __restrict__ anchors,
                                                const float* __restrict__ gt_boxes,
                                                const int* __restrict__ gt_labels,
                                                const float* __restrict__ pred_deltas,
                                                const unsigned int* __restrict__ maxpg,
                                                int* __restrict__ flags,
                                                double* __restrict__ acc,
                                                int R, int G) {
  __shared__ float4 sgt[64];
  __shared__ float sga[64];
  __shared__ int slab[64];
  __shared__ float smax[64];
  const int b = blockIdx.y;
  const int tid = threadIdx.x;
  if (tid < G) {
    const float4 gb = *(const float4*)(gt_boxes + ((size_t)b * G + tid) * 4);
    sgt[tid] = gb;
    sga[tid] = box_area_nc(gb.x, gb.y, gb.z, gb.w);
    slab[tid] = gt_labels[b * G + tid];
    smax[tid] = __uint_as_float(maxpg[b * G + tid]);
  }
  __syncthreads();
  const int r = blockIdx.x * blockDim.x + tid;
  float fgf = 0.0f, boxl = 0.0f;
  if (r < R) {
    const float4 a = *(const float4*)(anchors + (size_t)r * 4);
    const float aarea = box_area_nc(a.x, a.y, a.z, a.w);
    float best = 0.0f; int arg = 0; bool lq = false;
    for (int g = 0; g < G; ++g) {
      const float4 gb = sgt[g];
      const float iou = iou_nc(a.x, a.y, a.z, a.w, aarea, gb.x, gb.y, gb.z, gb.w, sga[g]);
      if (iou > best) { best = iou; arg = g; }  // strict > keeps first occurrence (argmax semantics)
      const float mg = smax[g];
      lq = lq || ((iou == mg) && (mg > 0.0f));
    }
    const bool fg = (best >= FG_T) || lq;
    const bool valid = fg || (best < BG_T);  // fg | ~ignore
    flags[(size_t)b * R + r] = (valid ? 1 : 0) | (fg ? 2 : 0) | (slab[arg] << 2);
    if (fg) {
      fgf = 1.0f;
      const float4 gb = sgt[arg];
      const float sw = a.z - a.x, sh = a.w - a.y;
      const float scx = a.x + 0.5f * sw, scy = a.y + 0.5f * sh;
      const float tw = gb.z - gb.x, th = gb.w - gb.y;
      const float tcx = gb.x + 0.5f * tw, tcy = gb.y + 0.5f * th;
      const float g0 = (tcx - scx) / sw;
      const float g1 = (tcy - scy) / sh;
      const float g2 = logf(tw / sw);
      const float g3 = logf(th / sh);
      const float4 pd = *(const float4*)(pred_deltas + ((size_t)b * R + r) * 4);
      float d[4] = {pd.x - g0, pd.y - g1, pd.z - g2, pd.w - g3};
#pragma unroll
      for (int k = 0; k < 4; ++k) {
        const float ad = fabsf(d[k]);
        boxl += (ad < BETA_C) ? (0.5f * d[k] * d[k] / BETA_C) : (ad - 0.5f * BETA_C);
      }
    }
  }
  // block reduce (wave shuffle + LDS across 4 waves)
  for (int off = 32; off > 0; off >>= 1) {
    fgf += __shfl_xor(fgf, off, 64);
    boxl += __shfl_xor(boxl, off, 64);
  }
  __shared__ float sred[8];
  const int wv = tid >> 6;
  if ((tid & 63) == 0) { sred[wv] = fgf; sred[4 + wv] = boxl; }
  __syncthreads();
  if (tid == 0) {
    atomicAdd(&acc[0], (double)(sred[0] + sred[1] + sred[2] + sred[3]));
    atomicAdd(&acc[2], (double)(sred[4] + sred[5] + sred[6] + sred[7]));
  }
}

// ---- kernel 3: focal loss over [B,R,C] via float4 ----
__global__ __launch_bounds__(256) void k_focal(const float* __restrict__ logits,
                                               const int* __restrict__ flags,
                                               double* __restrict__ acc,
                                               int total4) {
  const int i = blockIdx.x * blockDim.x + threadIdx.x;
  float s = 0.0f;
  if (i < total4) {
    const float4 x4 = ((const float4*)logits)[i];
    const int e0 = i * 4;          // NCLS % 4 == 0 -> the 4 elems share one anchor
    const int a = e0 / NCLS;
    const int c0 = e0 - a * NCLS;
    const int f = flags[a];
    if (f & 1) {                   // valid anchor
      const bool fg = (f & 2) != 0;
      const int label = f >> 2;
      const float xs[4] = {x4.x, x4.y, x4.z, x4.w};
#pragma unroll
      for (int k = 0; k < 4; ++k) {
        const float x = xs[k];
        const float t = (fg && (c0 + k) == label) ? 1.0f : 0.0f;
        const float p = 1.0f / (1.0f + expf(-x));
        const float ce = fmaxf(x, 0.0f) - x * t + log1pf(expf(-fabsf(x)));
        const float pt = p * t + (1.0f - p) * (1.0f - t);
        const float at = 0.25f * t + 0.75f * (1.0f - t);
        const float om = 1.0f - pt;
        s += ce * om * om * at;
      }
    }
  }
  for (int off = 32; off > 0; off >>= 1) s += __shfl_xor(s, off, 64);
  __shared__ float sred[4];
  if ((threadIdx.x & 63) == 0) sred[threadIdx.x >> 6] = s;
  __syncthreads();
  if (threadIdx.x == 0)
    atomicAdd(&acc[1], (double)(sred[0] + sred[1] + sred[2] + sred[3]));
}

// ---- kernel 4: finalize ----
__global__ void k_final(const double* __restrict__ acc, float* __restrict__ out) {
  if (threadIdx.x == 0) {
    const double norm = acc[0] > 1.0 ? acc[0] : 1.0;
    out[0] = (float)(acc[1] / norm);
    out[1] = (float)(acc[2] / norm);
  }
}

extern "C" void kernel_launch(void* const* d_in, const int* in_sizes, int n_in,
                              void* d_out, int out_size, void* d_ws, size_t ws_size,
                              hipStream_t stream) {
  const float* logits  = (const float*)d_in[0];   // [B,R,C]
  const float* deltas  = (const float*)d_in[1];   // [B,R,4]
  const float* anchors = (const float*)d_in[2];   // [R,4]
  const float* gtb     = (const float*)d_in[3];   // [B,G,4]
  const int*   gtl     = (const int*)d_in[4];     // [B,G]
  const int R = in_sizes[2] / 4;
  const int B = in_sizes[1] / (4 * R);
  const int G = in_sizes[4] / B;
  const int C = in_sizes[0] / (B * R);  // 80 (NCLS)
  float* out = (float*)d_out;
  (void)C; (void)n_in; (void)ws_size; (void)out_size;

  char* w = (char*)d_ws;
  double* acc = (double*)w;                        // acc[0]=num_fg acc[1]=cls acc[2]=box
  unsigned int* maxpg = (unsigned int*)(w + 64);   // [B*G]
  int* flags = (int*)(w + 2048);                   // [B*R]

  const int ninit = B * G;
  k_init<<<(ninit + 255) / 256, 256, 0, stream>>>(acc, maxpg, ninit);

  const int CH = 64;  // anchors per wave
  dim3 gB((R + 4 * CH - 1) / (4 * CH), B);
  k_maxpg<<<gB, 256, 0, stream>>>(anchors, gtb, maxpg, R, G, CH);

  dim3 gC((R + 255) / 256, B);
  k_assign<<<gC, 256, 0, stream>>>(anchors, gtb, gtl, deltas, maxpg, flags, acc, R, G);

  const int total4 = (B * R * C) / 4;
  k_focal<<<(total4 + 255) / 256, 256, 0, stream>>>(logits, flags, acc, total4);

  k_final<<<1, 64, 0, stream>>>(acc, out);
}

// Round 4
// 186.354 us; speedup vs baseline: 3.2305x; 3.2305x over previous
//
#include <hip/hip_runtime.h>
#include <math.h>

static constexpr int NCLS = 80;
#define FG_T 0.5f
#define BG_T 0.4f
#define BETA_C 0.1f

// ---- bit-stable IoU helpers (no FMA contraction so that both passes and
// ---- the NumPy reference produce bit-identical float32 values) ----
__device__ __forceinline__ float box_area_nc(float x1, float y1, float x2, float y2) {
#pragma clang fp contract(off)
  return (x2 - x1) * (y2 - y1);
}

__device__ __forceinline__ float iou_nc(float ax1, float ay1, float ax2, float ay2, float aarea,
                                        float gx1, float gy1, float gx2, float gy2, float garea) {
#pragma clang fp contract(off)
  float lx = fmaxf(ax1, gx1);
  float ly = fmaxf(ay1, gy1);
  float rx = fminf(ax2, gx2);
  float ry = fminf(ay2, gy2);
  float w = fmaxf(rx - lx, 0.0f);
  float h = fmaxf(ry - ly, 0.0f);
  float inter = w * h;
  return inter / (aarea + garea - inter);
}

// ---- kernel 0: zero accumulators + per-gt max array ----
__global__ void k_init(double* acc, unsigned int* maxpg, int n) {
  int i = blockIdx.x * blockDim.x + threadIdx.x;
  if (i < 4) acc[i] = 0.0;
  if (i < n) maxpg[i] = 0u;
}

// ---- kernel 1: max IoU per gt (lane = gt index, one wave per anchor chunk) ----
__global__ __launch_bounds__(256) void k_maxpg(const float* __restrict__ anchors,
                                               const float* __restrict__ gt_boxes,
                                               unsigned int* __restrict__ maxpg,
                                               int R, int G, int CH) {
  const int lane = threadIdx.x & 63;
  const int wid = blockIdx.x * (blockDim.x >> 6) + (threadIdx.x >> 6);
  const int b = blockIdx.y;
  const int r0 = wid * CH;
  if (r0 >= R) return;
  float gx1 = 0.f, gy1 = 0.f, gx2 = 0.f, gy2 = 0.f, garea = 0.f;
  if (lane < G) {
    const float4 gb = *(const float4*)(gt_boxes + ((size_t)b * G + lane) * 4);
    gx1 = gb.x; gy1 = gb.y; gx2 = gb.z; gy2 = gb.w;
    garea = box_area_nc(gx1, gy1, gx2, gy2);
  }
  float m = 0.0f;
  const int r1 = min(r0 + CH, R);
  for (int r = r0; r < r1; ++r) {
    const float4 a = *(const float4*)(anchors + (size_t)r * 4);
    const float aarea = box_area_nc(a.x, a.y, a.z, a.w);
    const float iou = iou_nc(a.x, a.y, a.z, a.w, aarea, gx1, gy1, gx2, gy2, garea);
    m = fmaxf(m, iou);
  }
  if (lane < G) atomicMax(&maxpg[b * G + lane], __float_as_uint(m));  // iou >= 0
}

// ---- kernel 2: per-anchor assignment + smooth L1 + fg count ----
__global__ __launch_bounds__(256) void k_assign(const float* __restrict__ anchors,
                                                const float* __restrict__ gt_boxes,
                                                const int* __restrict__ gt_labels,
                                                const float* __restrict__ pred_deltas,
                                                const unsigned int* __restrict__ maxpg,
                                                int* __restrict__ flags,
                                                double* __restrict__ acc,
                                                int R, int G) {
  __shared__ float4 sgt[64];
  __shared__ float sga[64];
  __shared__ int slab[64];
  __shared__ float smax[64];
  const int b = blockIdx.y;
  const int tid = threadIdx.x;
  if (tid < G) {
    const float4 gb = *(const float4*)(gt_boxes + ((size_t)b * G + tid) * 4);
    sgt[tid] = gb;
    sga[tid] = box_area_nc(gb.x, gb.y, gb.z, gb.w);
    slab[tid] = gt_labels[b * G + tid];
    smax[tid] = __uint_as_float(maxpg[b * G + tid]);
  }
  __syncthreads();
  const int r = blockIdx.x * blockDim.x + tid;
  float fgf = 0.0f, boxl = 0.0f;
  if (r < R) {
    const float4 a = *(const float4*)(anchors + (size_t)r * 4);
    const float aarea = box_area_nc(a.x, a.y, a.z, a.w);
    float best = 0.0f; int arg = 0; bool lq = false;
    for (int g = 0; g < G; ++g) {
      const float4 gb = sgt[g];
      const float iou = iou_nc(a.x, a.y, a.z, a.w, aarea, gb.x, gb.y, gb.z, gb.w, sga[g]);
      if (iou > best) { best = iou; arg = g; }  // strict > keeps first occurrence (argmax semantics)
      const float mg = smax[g];
      lq = lq || ((iou == mg) && (mg > 0.0f));
    }
    const bool fg = (best >= FG_T) || lq;
    const bool valid = fg || (best < BG_T);  // fg | ~ignore
    flags[(size_t)b * R + r] = (valid ? 1 : 0) | (fg ? 2 : 0) | (slab[arg] << 2);
    if (fg) {
      fgf = 1.0f;
      const float4 gb = sgt[arg];
      const float sw = a.z - a.x, sh = a.w - a.y;
      const float scx = a.x + 0.5f * sw, scy = a.y + 0.5f * sh;
      const float tw = gb.z - gb.x, th = gb.w - gb.y;
      const float tcx = gb.x + 0.5f * tw, tcy = gb.y + 0.5f * th;
      const float g0 = (tcx - scx) / sw;
      const float g1 = (tcy - scy) / sh;
      const float g2 = logf(tw / sw);
      const float g3 = logf(th / sh);
      const float4 pd = *(const float4*)(pred_deltas + ((size_t)b * R + r) * 4);
      float d[4] = {pd.x - g0, pd.y - g1, pd.z - g2, pd.w - g3};
#pragma unroll
      for (int k = 0; k < 4; ++k) {
        const float ad = fabsf(d[k]);
        boxl += (ad < BETA_C) ? (0.5f * d[k] * d[k] / BETA_C) : (ad - 0.5f * BETA_C);
      }
    }
  }
  // block reduce (wave shuffle + LDS across 4 waves)
  for (int off = 32; off > 0; off >>= 1) {
    fgf += __shfl_xor(fgf, off, 64);
    boxl += __shfl_xor(boxl, off, 64);
  }
  __shared__ float sred[8];
  const int wv = tid >> 6;
  if ((tid & 63) == 0) { sred[wv] = fgf; sred[4 + wv] = boxl; }
  __syncthreads();
  if (tid == 0) {
    atomicAdd(&acc[0], (double)(sred[0] + sred[1] + sred[2] + sred[3]));
    atomicAdd(&acc[2], (double)(sred[4] + sred[5] + sred[6] + sred[7]));
  }
}

// ---- fast focal element: raw v_exp/v_log/v_rcp (1-ulp), ~17 VALU ops ----
__device__ __forceinline__ float focal_elem(float x, bool t) {
  const float ax = fabsf(x);
  const float em = __builtin_amdgcn_exp2f(ax * -1.44269504088896340736f);  // exp(-|x|)
  const float opem = 1.0f + em;
  const float r = __builtin_amdgcn_rcpf(opem);       // 1/(1+em) = sigmoid(|x|)
  const float p = (x >= 0.0f) ? r : em * r;          // sigmoid(x)
  const float L = 0.693147180559945f * __builtin_amdgcn_logf(opem);  // log1p(exp(-|x|))
  const float ce = fmaxf(x, 0.0f) - (t ? x : 0.0f) + L;
  const float om = t ? (1.0f - p) : p;               // 1 - p_t
  const float at = t ? 0.25f : 0.75f;
  return ce * om * om * at;
}

// ---- kernel 3: focal loss over [B,R,C], grid-stride float4 ----
__global__ __launch_bounds__(256) void k_focal(const float4* __restrict__ logits4,
                                               const int* __restrict__ flags,
                                               double* __restrict__ acc,
                                               int total4) {
  const int stride = gridDim.x * blockDim.x;
  float s = 0.0f;
  for (int i = blockIdx.x * blockDim.x + threadIdx.x; i < total4; i += stride) {
    const float4 x4 = logits4[i];
    const int a = i / 20;                 // NCLS=80, 4 elems/chunk -> 20 chunks/anchor
    const int c0 = (i - a * 20) * 4;
    const int f = flags[a];
    if (f & 1) {                          // valid anchor
      const bool fg = (f & 2) != 0;
      const int label = f >> 2;
      s += focal_elem(x4.x, fg && (c0 + 0) == label);
      s += focal_elem(x4.y, fg && (c0 + 1) == label);
      s += focal_elem(x4.z, fg && (c0 + 2) == label);
      s += focal_elem(x4.w, fg && (c0 + 3) == label);
    }
  }
  for (int off = 32; off > 0; off >>= 1) s += __shfl_xor(s, off, 64);
  __shared__ float sred[4];
  if ((threadIdx.x & 63) == 0) sred[threadIdx.x >> 6] = s;
  __syncthreads();
  if (threadIdx.x == 0)
    atomicAdd(&acc[1], (double)(sred[0] + sred[1] + sred[2] + sred[3]));
}

// ---- kernel 4: finalize ----
__global__ void k_final(const double* __restrict__ acc, float* __restrict__ out) {
  if (threadIdx.x == 0) {
    const double norm = acc[0] > 1.0 ? acc[0] : 1.0;
    out[0] = (float)(acc[1] / norm);
    out[1] = (float)(acc[2] / norm);
  }
}

extern "C" void kernel_launch(void* const* d_in, const int* in_sizes, int n_in,
                              void* d_out, int out_size, void* d_ws, size_t ws_size,
                              hipStream_t stream) {
  const float* logits  = (const float*)d_in[0];   // [B,R,C]
  const float* deltas  = (const float*)d_in[1];   // [B,R,4]
  const float* anchors = (const float*)d_in[2];   // [R,4]
  const float* gtb     = (const float*)d_in[3];   // [B,G,4]
  const int*   gtl     = (const int*)d_in[4];     // [B,G]
  const int R = in_sizes[2] / 4;
  const int B = in_sizes[1] / (4 * R);
  const int G = in_sizes[4] / B;
  const int C = in_sizes[0] / (B * R);  // 80 (NCLS)
  float* out = (float*)d_out;
  (void)C; (void)n_in; (void)ws_size; (void)out_size;

  char* w = (char*)d_ws;
  double* acc = (double*)w;                        // acc[0]=num_fg acc[1]=cls acc[2]=box
  unsigned int* maxpg = (unsigned int*)(w + 64);   // [B*G]
  int* flags = (int*)(w + 2048);                   // [B*R]

  const int ninit = B * G;
  k_init<<<(ninit + 255) / 256, 256, 0, stream>>>(acc, maxpg, ninit);

  const int CH = 64;  // anchors per wave
  dim3 gB((R + 4 * CH - 1) / (4 * CH), B);
  k_maxpg<<<gB, 256, 0, stream>>>(anchors, gtb, maxpg, R, G, CH);

  dim3 gC((R + 255) / 256, B);
  k_assign<<<gC, 256, 0, stream>>>(anchors, gtb, gtl, deltas, maxpg, flags, acc, R, G);

  const int total4 = (B * R * C) / 4;
  int fblocks = (total4 + 255) / 256;
  if (fblocks > 2048) fblocks = 2048;   // grid-stride, 32 waves/CU, 2048 atomics total
  k_focal<<<fblocks, 256, 0, stream>>>((const float4*)logits, flags, acc, total4);

  k_final<<<1, 64, 0, stream>>>(acc, out);
}

// Round 5
// 175.983 us; speedup vs baseline: 3.4209x; 1.0589x over previous
//
#include <hip/hip_runtime.h>
#include <math.h>

static constexpr int NCLS = 80;
#define FG_T 0.5f
#define BG_T 0.4f
#define BETA_C 0.1f

// ---- bit-stable IoU helpers. Both matching passes inline THIS function, so
// ---- both produce bit-identical float32 IoU values (required for the
// ---- `iou == max_per_gt` low-quality-match equality). Fast v_rcp_f32 (1-ulp)
// ---- instead of the precise IEEE divide: internal consistency is what
// ---- matters, not agreement with NumPy's divide, and 1e-7 relative error
// ---- cannot flip 0.4/0.5 threshold tests on random data.
__device__ __forceinline__ float box_area_nc(float x1, float y1, float x2, float y2) {
#pragma clang fp contract(off)
  return (x2 - x1) * (y2 - y1);
}

__device__ __forceinline__ float iou_nc(float ax1, float ay1, float ax2, float ay2, float aarea,
                                        float gx1, float gy1, float gx2, float gy2, float garea) {
#pragma clang fp contract(off)
  float lx = fmaxf(ax1, gx1);
  float ly = fmaxf(ay1, gy1);
  float rx = fminf(ax2, gx2);
  float ry = fminf(ay2, gy2);
  float w = fmaxf(rx - lx, 0.0f);
  float h = fmaxf(ry - ly, 0.0f);
  float inter = w * h;
  return inter * __builtin_amdgcn_rcpf(aarea + garea - inter);
}

// ---- kernel 0: zero accumulators + per-gt max array ----
__global__ void k_init(double* acc, unsigned int* maxpg, int n) {
  int i = blockIdx.x * blockDim.x + threadIdx.x;
  if (i < 4) acc[i] = 0.0;
  if (i < n) maxpg[i] = 0u;
}

// ---- kernel 1: max IoU per gt (lane = gt index, one wave per anchor chunk) ----
__global__ __launch_bounds__(256) void k_maxpg(const float* __restrict__ anchors,
                                               const float* __restrict__ gt_boxes,
                                               unsigned int* __restrict__ maxpg,
                                               int R, int G, int CH) {
  const int lane = threadIdx.x & 63;
  const int wid = blockIdx.x * (blockDim.x >> 6) + (threadIdx.x >> 6);
  const int b = blockIdx.y;
  const int r0 = wid * CH;
  if (r0 >= R) return;
  float gx1 = 0.f, gy1 = 0.f, gx2 = 0.f, gy2 = 0.f, garea = 0.f;
  if (lane < G) {
    const float4 gb = *(const float4*)(gt_boxes + ((size_t)b * G + lane) * 4);
    gx1 = gb.x; gy1 = gb.y; gx2 = gb.z; gy2 = gb.w;
    garea = box_area_nc(gx1, gy1, gx2, gy2);
  }
  float m = 0.0f;
  const int r1 = min(r0 + CH, R);
#pragma unroll 4
  for (int r = r0; r < r1; ++r) {
    const float4 a = *(const float4*)(anchors + (size_t)r * 4);
    const float aarea = box_area_nc(a.x, a.y, a.z, a.w);
    const float iou = iou_nc(a.x, a.y, a.z, a.w, aarea, gx1, gy1, gx2, gy2, garea);
    m = fmaxf(m, iou);
  }
  if (lane < G) atomicMax(&maxpg[b * G + lane], __float_as_uint(m));  // iou >= 0
}

// ---- kernel 2: per-anchor assignment + smooth L1 + fg count ----
__global__ __launch_bounds__(256) void k_assign(const float* __restrict__ anchors,
                                                const float* __restrict__ gt_boxes,
                                                const int* __restrict__ gt_labels,
                                                const float* __restrict__ pred_deltas,
                                                const unsigned int* __restrict__ maxpg,
                                                int* __restrict__ flags,
                                                double* __restrict__ acc,
                                                int R, int G) {
  __shared__ float4 sgt[64];
  __shared__ float sga[64];
  __shared__ int slab[64];
  __shared__ float smax[64];
  const int b = blockIdx.y;
  const int tid = threadIdx.x;
  if (tid < G) {
    const float4 gb = *(const float4*)(gt_boxes + ((size_t)b * G + tid) * 4);
    sgt[tid] = gb;
    sga[tid] = box_area_nc(gb.x, gb.y, gb.z, gb.w);
    slab[tid] = gt_labels[b * G + tid];
    smax[tid] = __uint_as_float(maxpg[b * G + tid]);
  }
  __syncthreads();
  const int r = blockIdx.x * blockDim.x + tid;
  float fgf = 0.0f, boxl = 0.0f;
  if (r < R) {
    const float4 a = *(const float4*)(anchors + (size_t)r * 4);
    const float aarea = box_area_nc(a.x, a.y, a.z, a.w);
    float best = 0.0f; int arg = 0; bool lq = false;
#pragma unroll 4
    for (int g = 0; g < G; ++g) {
      const float4 gb = sgt[g];
      const float iou = iou_nc(a.x, a.y, a.z, a.w, aarea, gb.x, gb.y, gb.z, gb.w, sga[g]);
      if (iou > best) { best = iou; arg = g; }  // strict > keeps first occurrence (argmax semantics)
      const float mg = smax[g];
      lq = lq || ((iou == mg) && (mg > 0.0f));
    }
    const bool fg = (best >= FG_T) || lq;
    const bool valid = fg || (best < BG_T);  // fg | ~ignore
    flags[(size_t)b * R + r] = (valid ? 1 : 0) | (fg ? 2 : 0) | (slab[arg] << 2);
    if (fg) {
      fgf = 1.0f;
      const float4 gb = sgt[arg];
      const float sw = a.z - a.x, sh = a.w - a.y;
      const float scx = a.x + 0.5f * sw, scy = a.y + 0.5f * sh;
      const float tw = gb.z - gb.x, th = gb.w - gb.y;
      const float tcx = gb.x + 0.5f * tw, tcy = gb.y + 0.5f * th;
      const float g0 = (tcx - scx) * __builtin_amdgcn_rcpf(sw);
      const float g1 = (tcy - scy) * __builtin_amdgcn_rcpf(sh);
      const float g2 = 0.6931471805599453f * __builtin_amdgcn_logf(tw * __builtin_amdgcn_rcpf(sw));
      const float g3 = 0.6931471805599453f * __builtin_amdgcn_logf(th * __builtin_amdgcn_rcpf(sh));
      const float4 pd = *(const float4*)(pred_deltas + ((size_t)b * R + r) * 4);
      float d[4] = {pd.x - g0, pd.y - g1, pd.z - g2, pd.w - g3};
#pragma unroll
      for (int k = 0; k < 4; ++k) {
        const float ad = fabsf(d[k]);
        boxl += (ad < BETA_C) ? (5.0f * d[k] * d[k]) : (ad - 0.5f * BETA_C);
      }
    }
  }
  // block reduce (wave shuffle + LDS across 4 waves)
  for (int off = 32; off > 0; off >>= 1) {
    fgf += __shfl_xor(fgf, off, 64);
    boxl += __shfl_xor(boxl, off, 64);
  }
  __shared__ float sred[8];
  const int wv = tid >> 6;
  if ((tid & 63) == 0) { sred[wv] = fgf; sred[4 + wv] = boxl; }
  __syncthreads();
  if (tid == 0) {
    atomicAdd(&acc[0], (double)(sred[0] + sred[1] + sred[2] + sred[3]));
    atomicAdd(&acc[2], (double)(sred[4] + sred[5] + sred[6] + sred[7]));
  }
}

// ---- fast focal element: raw v_exp/v_log/v_rcp (1-ulp), ~17 VALU ops ----
__device__ __forceinline__ float focal_elem(float x, bool t) {
  const float ax = fabsf(x);
  const float em = __builtin_amdgcn_exp2f(ax * -1.44269504088896340736f);  // exp(-|x|)
  const float opem = 1.0f + em;
  const float r = __builtin_amdgcn_rcpf(opem);       // 1/(1+em) = sigmoid(|x|)
  const float p = (x >= 0.0f) ? r : em * r;          // sigmoid(x)
  const float L = 0.693147180559945f * __builtin_amdgcn_logf(opem);  // log1p(exp(-|x|))
  const float ce = fmaxf(x, 0.0f) - (t ? x : 0.0f) + L;
  const float om = t ? (1.0f - p) : p;               // 1 - p_t
  const float at = t ? 0.25f : 0.75f;
  return ce * om * om * at;
}

// ---- kernel 3: focal loss over [B,R,C], grid-stride float4 ----
__global__ __launch_bounds__(256) void k_focal(const float4* __restrict__ logits4,
                                               const int* __restrict__ flags,
                                               double* __restrict__ acc,
                                               int total4) {
  const int stride = gridDim.x * blockDim.x;
  float s = 0.0f;
  for (int i = blockIdx.x * blockDim.x + threadIdx.x; i < total4; i += stride) {
    const float4 x4 = logits4[i];
    const int a = i / 20;                 // NCLS=80, 4 elems/chunk -> 20 chunks/anchor
    const int c0 = (i - a * 20) * 4;
    const int f = flags[a];
    if (f & 1) {                          // valid anchor
      const bool fg = (f & 2) != 0;
      const int label = f >> 2;
      s += focal_elem(x4.x, fg && (c0 + 0) == label);
      s += focal_elem(x4.y, fg && (c0 + 1) == label);
      s += focal_elem(x4.z, fg && (c0 + 2) == label);
      s += focal_elem(x4.w, fg && (c0 + 3) == label);
    }
  }
  for (int off = 32; off > 0; off >>= 1) s += __shfl_xor(s, off, 64);
  __shared__ float sred[4];
  if ((threadIdx.x & 63) == 0) sred[threadIdx.x >> 6] = s;
  __syncthreads();
  if (threadIdx.x == 0)
    atomicAdd(&acc[1], (double)(sred[0] + sred[1] + sred[2] + sred[3]));
}

// ---- kernel 4: finalize ----
__global__ void k_final(const double* __restrict__ acc, float* __restrict__ out) {
  if (threadIdx.x == 0) {
    const double norm = acc[0] > 1.0 ? acc[0] : 1.0;
    out[0] = (float)(acc[1] / norm);
    out[1] = (float)(acc[2] / norm);
  }
}

extern "C" void kernel_launch(void* const* d_in, const int* in_sizes, int n_in,
                              void* d_out, int out_size, void* d_ws, size_t ws_size,
                              hipStream_t stream) {
  const float* logits  = (const float*)d_in[0];   // [B,R,C]
  const float* deltas  = (const float*)d_in[1];   // [B,R,4]
  const float* anchors = (const float*)d_in[2];   // [R,4]
  const float* gtb     = (const float*)d_in[3];   // [B,G,4]
  const int*   gtl     = (const int*)d_in[4];     // [B,G]
  const int R = in_sizes[2] / 4;
  const int B = in_sizes[1] / (4 * R);
  const int G = in_sizes[4] / B;
  const int C = in_sizes[0] / (B * R);  // 80 (NCLS)
  float* out = (float*)d_out;
  (void)C; (void)n_in; (void)ws_size; (void)out_size;

  char* w = (char*)d_ws;
  double* acc = (double*)w;                        // acc[0]=num_fg acc[1]=cls acc[2]=box
  unsigned int* maxpg = (unsigned int*)(w + 64);   // [B*G]
  int* flags = (int*)(w + 2048);                   // [B*R]

  const int ninit = B * G;
  k_init<<<(ninit + 255) / 256, 256, 0, stream>>>(acc, maxpg, ninit);

  const int CH = 64;  // anchors per wave
  dim3 gB((R + 4 * CH - 1) / (4 * CH), B);
  k_maxpg<<<gB, 256, 0, stream>>>(anchors, gtb, maxpg, R, G, CH);

  dim3 gC((R + 255) / 256, B);
  k_assign<<<gC, 256, 0, stream>>>(anchors, gtb, gtl, deltas, maxpg, flags, acc, R, G);

  const int total4 = (B * R * C) / 4;
  int fblocks = (total4 + 255) / 256;
  if (fblocks > 2048) fblocks = 2048;   // grid-stride, 32 waves/CU, 2048 atomics total
  k_focal<<<fblocks, 256, 0, stream>>>((const float4*)logits, flags, acc, total4);

  k_final<<<1, 64, 0, stream>>>(acc, out);
}

// Round 6
// 94.395 us; speedup vs baseline: 6.3777x; 1.8643x over previous
//
#include <hip/hip_runtime.h>
#include <math.h>

static constexpr int NCLS = 80;
#define FG_T 0.5f
#define BG_T 0.4f
#define BETA_C 0.1f

// ---- bit-stable IoU helpers. Both matching passes inline THIS function, so
// ---- both produce bit-identical float32 IoU values (required for the
// ---- `iou == max_per_gt` low-quality-match equality).
__device__ __forceinline__ float box_area_nc(float x1, float y1, float x2, float y2) {
#pragma clang fp contract(off)
  return (x2 - x1) * (y2 - y1);
}

__device__ __forceinline__ float iou_nc(float ax1, float ay1, float ax2, float ay2, float aarea,
                                        float gx1, float gy1, float gx2, float gy2, float garea) {
#pragma clang fp contract(off)
  float lx = fmaxf(ax1, gx1);
  float ly = fmaxf(ay1, gy1);
  float rx = fminf(ax2, gx2);
  float ry = fminf(ay2, gy2);
  float w = fmaxf(rx - lx, 0.0f);
  float h = fmaxf(ry - ly, 0.0f);
  float inter = w * h;
  return inter * __builtin_amdgcn_rcpf(aarea + garea - inter);
}

// ws layout: accFG double[32] @0, accCLS double[32] @256, accBOX double[32] @512,
//            maxpg uint[256] @1024, flags int[B*R] @4096

// ---- kernel 0: zero accumulator slots + per-gt max array (1 block, 256 thr) ----
__global__ void k_init(double* acc, unsigned int* maxpg, int n) {
  const int i = threadIdx.x;
  if (i < 96) acc[i] = 0.0;
  if (i < n) maxpg[i] = 0u;
}

// ---- kernel 1: max IoU per gt; lane=gt, wave per anchor chunk, block-level
// ---- LDS combine -> ONE atomicMax per (block, gt) instead of per (wave, gt).
__global__ __launch_bounds__(256) void k_maxpg(const float* __restrict__ anchors,
                                               const float* __restrict__ gt_boxes,
                                               unsigned int* __restrict__ maxpg,
                                               int R, int G, int CH) {
  const int lane = threadIdx.x & 63;
  const int wv = threadIdx.x >> 6;
  const int b = blockIdx.y;
  float gx1 = 0.f, gy1 = 0.f, gx2 = 0.f, gy2 = 0.f, garea = 0.f;
  if (lane < G) {
    const float4 gb = *(const float4*)(gt_boxes + ((size_t)b * G + lane) * 4);
    gx1 = gb.x; gy1 = gb.y; gx2 = gb.z; gy2 = gb.w;
    garea = box_area_nc(gx1, gy1, gx2, gy2);
  }
  float m = 0.0f;
  const int r0 = (blockIdx.x * 4 + wv) * CH;
  const int r1 = min(r0 + CH, R);
#pragma unroll 4
  for (int r = r0; r < r1; ++r) {   // uniform address -> scalarizable load
    const float4 a = *(const float4*)(anchors + (size_t)r * 4);
    const float aarea = box_area_nc(a.x, a.y, a.z, a.w);
    m = fmaxf(m, iou_nc(a.x, a.y, a.z, a.w, aarea, gx1, gy1, gx2, gy2, garea));
  }
  __shared__ float red[4][64];
  red[wv][lane] = m;
  __syncthreads();
  if (wv == 0 && lane < G) {
    const float mm = fmaxf(fmaxf(red[0][lane], red[1][lane]),
                           fmaxf(red[2][lane], red[3][lane]));
    if (mm > 0.0f) atomicMax(&maxpg[b * G + lane], __float_as_uint(mm));  // iou >= 0
  }
}

// ---- kernel 2: per-anchor assignment, 2 anchors per thread ----
__global__ __launch_bounds__(256) void k_assign(const float* __restrict__ anchors,
                                                const float* __restrict__ gt_boxes,
                                                const int* __restrict__ gt_labels,
                                                const float* __restrict__ pred_deltas,
                                                const unsigned int* __restrict__ maxpg,
                                                int* __restrict__ flags,
                                                double* __restrict__ accFG,
                                                double* __restrict__ accBOX,
                                                int R, int G) {
  __shared__ float4 sgt[64];
  __shared__ float2 sfa[64];   // (garea, max_per_gt)
  __shared__ int slab[64];
  const int b = blockIdx.y;
  const int tid = threadIdx.x;
  if (tid < G) {
    const float4 gb = *(const float4*)(gt_boxes + ((size_t)b * G + tid) * 4);
    sgt[tid] = gb;
    sfa[tid] = make_float2(box_area_nc(gb.x, gb.y, gb.z, gb.w),
                           __uint_as_float(maxpg[b * G + tid]));
    slab[tid] = gt_labels[b * G + tid];
  }
  __syncthreads();
  const int rA = blockIdx.x * 512 + tid;
  const int rB = rA + 256;
  const bool vA = rA < R, vB = rB < R;
  float4 a0 = make_float4(0.f, 0.f, 0.f, 0.f), a1 = a0;
  float ar0 = 0.f, ar1 = 0.f;
  if (vA) { a0 = *(const float4*)(anchors + (size_t)rA * 4); ar0 = box_area_nc(a0.x, a0.y, a0.z, a0.w); }
  if (vB) { a1 = *(const float4*)(anchors + (size_t)rB * 4); ar1 = box_area_nc(a1.x, a1.y, a1.z, a1.w); }
  float best0 = 0.f, best1 = 0.f;
  int arg0 = 0, arg1 = 0;
  bool lq0 = false, lq1 = false;
#pragma unroll 4
  for (int g = 0; g < G; ++g) {    // 2 LDS reads serve 2 anchors (~32 VALU)
    const float4 gb = sgt[g];
    const float2 fa = sfa[g];
    const float i0 = iou_nc(a0.x, a0.y, a0.z, a0.w, ar0, gb.x, gb.y, gb.z, gb.w, fa.x);
    const float i1 = iou_nc(a1.x, a1.y, a1.z, a1.w, ar1, gb.x, gb.y, gb.z, gb.w, fa.x);
    if (i0 > best0) { best0 = i0; arg0 = g; }
    if (i1 > best1) { best1 = i1; arg1 = g; }
    lq0 = lq0 || ((i0 == fa.y) && (fa.y > 0.0f));
    lq1 = lq1 || ((i1 == fa.y) && (fa.y > 0.0f));
  }
  float fgf = 0.0f, boxl = 0.0f;
#pragma unroll
  for (int k = 0; k < 2; ++k) {
    const bool v = k ? vB : vA;
    if (!v) continue;
    const float4 a = k ? a1 : a0;
    const float best = k ? best1 : best0;
    const int arg = k ? arg1 : arg0;
    const bool lq = k ? lq1 : lq0;
    const int r = k ? rB : rA;
    const bool fg = (best >= FG_T) || lq;
    const bool valid = fg || (best < BG_T);  // fg | ~ignore
    flags[(size_t)b * R + r] = (valid ? 1 : 0) | (fg ? 2 : 0) | (slab[arg] << 2);
    if (fg) {
      fgf += 1.0f;
      const float4 gb = sgt[arg];
      const float sw = a.z - a.x, sh = a.w - a.y;
      const float scx = a.x + 0.5f * sw, scy = a.y + 0.5f * sh;
      const float tw = gb.z - gb.x, th = gb.w - gb.y;
      const float tcx = gb.x + 0.5f * tw, tcy = gb.y + 0.5f * th;
      const float g0 = (tcx - scx) * __builtin_amdgcn_rcpf(sw);
      const float g1 = (tcy - scy) * __builtin_amdgcn_rcpf(sh);
      const float g2 = 0.6931471805599453f * __builtin_amdgcn_logf(tw * __builtin_amdgcn_rcpf(sw));
      const float g3 = 0.6931471805599453f * __builtin_amdgcn_logf(th * __builtin_amdgcn_rcpf(sh));
      const float4 pd = *(const float4*)(pred_deltas + ((size_t)b * R + r) * 4);
      const float d[4] = {pd.x - g0, pd.y - g1, pd.z - g2, pd.w - g3};
#pragma unroll
      for (int j = 0; j < 4; ++j) {
        const float ad = fabsf(d[j]);
        boxl += (ad < BETA_C) ? (5.0f * d[j] * d[j]) : (ad - 0.5f * BETA_C);
      }
    }
  }
  for (int off = 32; off > 0; off >>= 1) {
    fgf += __shfl_xor(fgf, off, 64);
    boxl += __shfl_xor(boxl, off, 64);
  }
  __shared__ float sred[8];
  const int wv = tid >> 6;
  if ((tid & 63) == 0) { sred[wv] = fgf; sred[4 + wv] = boxl; }
  __syncthreads();
  if (tid == 0) {
    const int slot = (blockIdx.y * gridDim.x + blockIdx.x) & 31;
    atomicAdd(&accFG[slot], (double)(sred[0] + sred[1] + sred[2] + sred[3]));
    atomicAdd(&accBOX[slot], (double)(sred[4] + sred[5] + sred[6] + sred[7]));
  }
}

// ---- fast focal element: raw v_exp/v_log/v_rcp (1-ulp), ~17 VALU ops ----
__device__ __forceinline__ float focal_elem(float x, bool t) {
  const float ax = fabsf(x);
  const float em = __builtin_amdgcn_exp2f(ax * -1.44269504088896340736f);  // exp(-|x|)
  const float opem = 1.0f + em;
  const float r = __builtin_amdgcn_rcpf(opem);
  const float p = (x >= 0.0f) ? r : em * r;          // sigmoid(x)
  const float L = 0.693147180559945f * __builtin_amdgcn_logf(opem);  // log1p(exp(-|x|))
  const float ce = fmaxf(x, 0.0f) - (t ? x : 0.0f) + L;
  const float om = t ? (1.0f - p) : p;               // 1 - p_t
  const float at = t ? 0.25f : 0.75f;
  return ce * om * om * at;
}

// ---- kernel 3: focal loss over [B,R,C], grid-stride float4 ----
__global__ __launch_bounds__(256) void k_focal(const float4* __restrict__ logits4,
                                               const int* __restrict__ flags,
                                               double* __restrict__ accCLS,
                                               int total4) {
  const int stride = gridDim.x * blockDim.x;
  float s = 0.0f;
  for (int i = blockIdx.x * blockDim.x + threadIdx.x; i < total4; i += stride) {
    const float4 x4 = logits4[i];
    const int a = i / 20;                 // NCLS=80 -> 20 float4 chunks per anchor
    const int c0 = (i - a * 20) * 4;
    const int f = flags[a];
    if (f & 1) {                          // valid anchor
      const bool fg = (f & 2) != 0;
      const int label = f >> 2;
      s += focal_elem(x4.x, fg && (c0 + 0) == label);
      s += focal_elem(x4.y, fg && (c0 + 1) == label);
      s += focal_elem(x4.z, fg && (c0 + 2) == label);
      s += focal_elem(x4.w, fg && (c0 + 3) == label);
    }
  }
  for (int off = 32; off > 0; off >>= 1) s += __shfl_xor(s, off, 64);
  __shared__ float sred[4];
  if ((threadIdx.x & 63) == 0) sred[threadIdx.x >> 6] = s;
  __syncthreads();
  if (threadIdx.x == 0)
    atomicAdd(&accCLS[blockIdx.x & 31], (double)(sred[0] + sred[1] + sred[2] + sred[3]));
}

// ---- kernel 4: finalize (sum 3x32 slots) ----
__global__ void k_final(const double* __restrict__ accFG, const double* __restrict__ accCLS,
                        const double* __restrict__ accBOX, float* __restrict__ out) {
  if (threadIdx.x == 0) {
    double fg = 0.0, cls = 0.0, box = 0.0;
    for (int i = 0; i < 32; ++i) { fg += accFG[i]; cls += accCLS[i]; box += accBOX[i]; }
    const double norm = fg > 1.0 ? fg : 1.0;
    out[0] = (float)(cls / norm);
    out[1] = (float)(box / norm);
  }
}

extern "C" void kernel_launch(void* const* d_in, const int* in_sizes, int n_in,
                              void* d_out, int out_size, void* d_ws, size_t ws_size,
                              hipStream_t stream) {
  const float* logits  = (const float*)d_in[0];   // [B,R,C]
  const float* deltas  = (const float*)d_in[1];   // [B,R,4]
  const float* anchors = (const float*)d_in[2];   // [R,4]
  const float* gtb     = (const float*)d_in[3];   // [B,G,4]
  const int*   gtl     = (const int*)d_in[4];     // [B,G]
  const int R = in_sizes[2] / 4;
  const int B = in_sizes[1] / (4 * R);
  const int G = in_sizes[4] / B;
  const int C = in_sizes[0] / (B * R);  // 80 (NCLS)
  float* out = (float*)d_out;
  (void)C; (void)n_in; (void)ws_size; (void)out_size;

  char* w = (char*)d_ws;
  double* accFG  = (double*)(w + 0);
  double* accCLS = (double*)(w + 256);
  double* accBOX = (double*)(w + 512);
  unsigned int* maxpg = (unsigned int*)(w + 1024);   // [B*G]
  int* flags = (int*)(w + 4096);                     // [B*R]

  k_init<<<1, 256, 0, stream>>>(accFG, maxpg, B * G);

  const int CH = 128;  // anchors per wave
  dim3 gB((R + 4 * CH - 1) / (4 * CH), B);
  k_maxpg<<<gB, 256, 0, stream>>>(anchors, gtb, maxpg, R, G, CH);

  dim3 gC((R + 511) / 512, B);
  k_assign<<<gC, 256, 0, stream>>>(anchors, gtb, gtl, deltas, maxpg, flags, accFG, accBOX, R, G);

  const int total4 = (B * R * C) / 4;
  int fblocks = (total4 + 255) / 256;
  if (fblocks > 2048) fblocks = 2048;   // grid-stride
  k_focal<<<fblocks, 256, 0, stream>>>((const float4*)logits, flags, accCLS, total4);

  k_final<<<1, 64, 0, stream>>>(accFG, accCLS, accBOX, out);
}

// Round 7
// 82.691 us; speedup vs baseline: 7.2804x; 1.1415x over previous
//
#include <hip/hip_runtime.h>
#include <math.h>

static constexpr int NCLS = 80;
#define FG_T 0.5f
#define BG_T 0.4f
#define BETA_C 0.1f

// ---- bit-stable IoU helpers. Both matching passes inline THIS function, so
// ---- both produce bit-identical float32 IoU values (required for the
// ---- `iou == max_per_gt` low-quality-match equality).
__device__ __forceinline__ float box_area_nc(float x1, float y1, float x2, float y2) {
#pragma clang fp contract(off)
  return (x2 - x1) * (y2 - y1);
}

__device__ __forceinline__ float iou_nc(float ax1, float ay1, float ax2, float ay2, float aarea,
                                        float gx1, float gy1, float gx2, float gy2, float garea) {
#pragma clang fp contract(off)
  float lx = fmaxf(ax1, gx1);
  float ly = fmaxf(ay1, gy1);
  float rx = fminf(ax2, gx2);
  float ry = fminf(ay2, gy2);
  float w = fmaxf(rx - lx, 0.0f);
  float h = fmaxf(ry - ly, 0.0f);
  float inter = w * h;
  return inter * __builtin_amdgcn_rcpf(aarea + garea - inter);
}

// ---- focal loss pieces (1-ulp HW transcendentals).
// Reference per-element focal with t=0:  ce=softplus(x), om=p,   at=0.75
//                          with t=1:  ce=softplus(-x), om=1-p, at=0.25
// (max(x,0)-x == max(-x,0); log1p(e^-|x|)+max(.,0) == softplus)
__device__ __forceinline__ float loss_bg(float x) {
  const float ax = fabsf(x);
  const float em = __builtin_amdgcn_exp2f(ax * -1.44269504088896340736f);  // e^-|x|
  const float opem = 1.0f + em;
  const float r = __builtin_amdgcn_rcpf(opem);
  const float p = (x >= 0.0f) ? r : em * r;                                // sigmoid(x)
  const float sp = fmaxf(x, 0.0f) + 0.6931471805599453f * __builtin_amdgcn_logf(opem);
  return 0.75f * sp * p * p;
}
__device__ __forceinline__ float loss_fg(float x) {
  const float ax = fabsf(x);
  const float em = __builtin_amdgcn_exp2f(ax * -1.44269504088896340736f);
  const float opem = 1.0f + em;
  const float r = __builtin_amdgcn_rcpf(opem);
  const float p = (x >= 0.0f) ? r : em * r;
  const float q = 1.0f - p;
  const float sp = fmaxf(-x, 0.0f) + 0.6931471805599453f * __builtin_amdgcn_logf(opem);
  return 0.25f * sp * q * q;
}

// ws layout: accFG double[32] @0, accCLS double[32] @256, accBOX double[32] @512,
//            maxpg uint[256] @1024

// ---- kernel 0: zero accumulator slots + per-gt max array ----
__global__ void k_init(double* acc, unsigned int* maxpg, int n) {
  const int i = threadIdx.x;
  if (i < 96) acc[i] = 0.0;
  if (i < n) maxpg[i] = 0u;
}

// ---- kernel 1: max IoU per gt; lane=gt, wave per anchor chunk, block-level
// ---- LDS combine -> ONE atomicMax per (block, gt).
__global__ __launch_bounds__(256) void k_maxpg(const float* __restrict__ anchors,
                                               const float* __restrict__ gt_boxes,
                                               unsigned int* __restrict__ maxpg,
                                               int R, int G, int CH) {
  const int lane = threadIdx.x & 63;
  const int wv = threadIdx.x >> 6;
  const int b = blockIdx.y;
  float gx1 = 0.f, gy1 = 0.f, gx2 = 0.f, gy2 = 0.f, garea = 0.f;
  if (lane < G) {
    const float4 gb = *(const float4*)(gt_boxes + ((size_t)b * G + lane) * 4);
    gx1 = gb.x; gy1 = gb.y; gx2 = gb.z; gy2 = gb.w;
    garea = box_area_nc(gx1, gy1, gx2, gy2);
  }
  float m = 0.0f;
  const int r0 = (blockIdx.x * 4 + wv) * CH;
  const int r1 = min(r0 + CH, R);
#pragma unroll 4
  for (int r = r0; r < r1; ++r) {   // uniform address -> scalarizable load
    const float4 a = *(const float4*)(anchors + (size_t)r * 4);
    const float aarea = box_area_nc(a.x, a.y, a.z, a.w);
    m = fmaxf(m, iou_nc(a.x, a.y, a.z, a.w, aarea, gx1, gy1, gx2, gy2, garea));
  }
  __shared__ float red[4][64];
  red[wv][lane] = m;
  __syncthreads();
  if (wv == 0 && lane < G) {
    const float mm = fmaxf(fmaxf(red[0][lane], red[1][lane]),
                           fmaxf(red[2][lane], red[3][lane]));
    if (mm > 0.0f) atomicMax(&maxpg[b * G + lane], __float_as_uint(mm));  // iou >= 0
  }
}

// ---- kernel 2: FUSED assignment + smooth-L1 + focal, 2 anchors per thread ----
__global__ __launch_bounds__(256) void k_fused(const float* __restrict__ anchors,
                                               const float* __restrict__ gt_boxes,
                                               const int* __restrict__ gt_labels,
                                               const float* __restrict__ pred_deltas,
                                               const float* __restrict__ logits,
                                               const unsigned int* __restrict__ maxpg,
                                               double* __restrict__ accFG,
                                               double* __restrict__ accCLS,
                                               double* __restrict__ accBOX,
                                               int R, int G) {
  __shared__ float4 sgt[64];
  __shared__ float2 sfa[64];   // (garea, max_per_gt)
  __shared__ int slab[64];
  const int b = blockIdx.y;
  const int tid = threadIdx.x;
  if (tid < G) {
    const float4 gb = *(const float4*)(gt_boxes + ((size_t)b * G + tid) * 4);
    sgt[tid] = gb;
    sfa[tid] = make_float2(box_area_nc(gb.x, gb.y, gb.z, gb.w),
                           __uint_as_float(maxpg[b * G + tid]));
    slab[tid] = gt_labels[b * G + tid];
  }
  __syncthreads();
  const int rA = blockIdx.x * 512 + tid;
  const int rB = rA + 256;
  const bool vA = rA < R, vB = rB < R;
  float4 a0 = make_float4(0.f, 0.f, 0.f, 0.f), a1 = a0;
  float ar0 = 0.f, ar1 = 0.f;
  if (vA) { a0 = *(const float4*)(anchors + (size_t)rA * 4); ar0 = box_area_nc(a0.x, a0.y, a0.z, a0.w); }
  if (vB) { a1 = *(const float4*)(anchors + (size_t)rB * 4); ar1 = box_area_nc(a1.x, a1.y, a1.z, a1.w); }
  float best0 = 0.f, best1 = 0.f;
  int arg0 = 0, arg1 = 0;
  bool lq0 = false, lq1 = false;
#pragma unroll 4
  for (int g = 0; g < G; ++g) {    // 2 LDS reads serve 2 anchors
    const float4 gb = sgt[g];
    const float2 fa = sfa[g];
    const float i0 = iou_nc(a0.x, a0.y, a0.z, a0.w, ar0, gb.x, gb.y, gb.z, gb.w, fa.x);
    const float i1 = iou_nc(a1.x, a1.y, a1.z, a1.w, ar1, gb.x, gb.y, gb.z, gb.w, fa.x);
    if (i0 > best0) { best0 = i0; arg0 = g; }
    if (i1 > best1) { best1 = i1; arg1 = g; }
    lq0 = lq0 || ((i0 == fa.y) && (fa.y > 0.0f));
    lq1 = lq1 || ((i1 == fa.y) && (fa.y > 0.0f));
  }
  float fgf = 0.0f, boxl = 0.0f, clsl = 0.0f;
#pragma unroll
  for (int k = 0; k < 2; ++k) {
    if (!(k ? vB : vA)) continue;
    const float4 a = k ? a1 : a0;
    const float best = k ? best1 : best0;
    const int arg = k ? arg1 : arg0;
    const bool lq = k ? lq1 : lq0;
    const int r = k ? rB : rA;
    const bool fg = (best >= FG_T) || lq;
    const bool valid = fg || (best < BG_T);  // fg | ~ignore
    const size_t row = ((size_t)b * R + r) * NCLS;
    if (valid) {
      // background focal over all 80 classes (uniform, no label compare)
      const float4* lrow = (const float4*)(logits + row);
      float cs = 0.0f;
#pragma unroll 5
      for (int c = 0; c < NCLS / 4; ++c) {
        const float4 x4 = lrow[c];
        cs += loss_bg(x4.x) + loss_bg(x4.y) + loss_bg(x4.z) + loss_bg(x4.w);
      }
      if (fg) {  // rare single-element correction at the label class
        const float xl = logits[row + slab[arg]];
        cs += loss_fg(xl) - loss_bg(xl);
      }
      clsl += cs;
    }
    if (fg) {
      fgf += 1.0f;
      const float4 gb = sgt[arg];
      const float sw = a.z - a.x, sh = a.w - a.y;
      const float scx = a.x + 0.5f * sw, scy = a.y + 0.5f * sh;
      const float tw = gb.z - gb.x, th = gb.w - gb.y;
      const float tcx = gb.x + 0.5f * tw, tcy = gb.y + 0.5f * th;
      const float g0 = (tcx - scx) * __builtin_amdgcn_rcpf(sw);
      const float g1 = (tcy - scy) * __builtin_amdgcn_rcpf(sh);
      const float g2 = 0.6931471805599453f * __builtin_amdgcn_logf(tw * __builtin_amdgcn_rcpf(sw));
      const float g3 = 0.6931471805599453f * __builtin_amdgcn_logf(th * __builtin_amdgcn_rcpf(sh));
      const float4 pd = *(const float4*)(pred_deltas + ((size_t)b * R + r) * 4);
      const float d[4] = {pd.x - g0, pd.y - g1, pd.z - g2, pd.w - g3};
#pragma unroll
      for (int j = 0; j < 4; ++j) {
        const float ad = fabsf(d[j]);
        boxl += (ad < BETA_C) ? (5.0f * d[j] * d[j]) : (ad - 0.5f * BETA_C);
      }
    }
  }
  for (int off = 32; off > 0; off >>= 1) {
    fgf += __shfl_xor(fgf, off, 64);
    boxl += __shfl_xor(boxl, off, 64);
    clsl += __shfl_xor(clsl, off, 64);
  }
  __shared__ float sred[12];
  const int wv = tid >> 6;
  if ((tid & 63) == 0) { sred[wv] = fgf; sred[4 + wv] = boxl; sred[8 + wv] = clsl; }
  __syncthreads();
  if (tid == 0) {
    const int slot = (blockIdx.y * gridDim.x + blockIdx.x) & 31;
    atomicAdd(&accFG[slot], (double)(sred[0] + sred[1] + sred[2] + sred[3]));
    atomicAdd(&accBOX[slot], (double)(sred[4] + sred[5] + sred[6] + sred[7]));
    atomicAdd(&accCLS[slot], (double)(sred[8] + sred[9] + sred[10] + sred[11]));
  }
}

// ---- kernel 3: finalize (sum 3x32 slots) ----
__global__ void k_final(const double* __restrict__ accFG, const double* __restrict__ accCLS,
                        const double* __restrict__ accBOX, float* __restrict__ out) {
  if (threadIdx.x == 0) {
    double fg = 0.0, cls = 0.0, box = 0.0;
    for (int i = 0; i < 32; ++i) { fg += accFG[i]; cls += accCLS[i]; box += accBOX[i]; }
    const double norm = fg > 1.0 ? fg : 1.0;
    out[0] = (float)(cls / norm);
    out[1] = (float)(box / norm);
  }
}

extern "C" void kernel_launch(void* const* d_in, const int* in_sizes, int n_in,
                              void* d_out, int out_size, void* d_ws, size_t ws_size,
                              hipStream_t stream) {
  const float* logits  = (const float*)d_in[0];   // [B,R,C]
  const float* deltas  = (const float*)d_in[1];   // [B,R,4]
  const float* anchors = (const float*)d_in[2];   // [R,4]
  const float* gtb     = (const float*)d_in[3];   // [B,G,4]
  const int*   gtl     = (const int*)d_in[4];     // [B,G]
  const int R = in_sizes[2] / 4;
  const int B = in_sizes[1] / (4 * R);
  const int G = in_sizes[4] / B;
  float* out = (float*)d_out;
  (void)n_in; (void)ws_size; (void)out_size;

  char* w = (char*)d_ws;
  double* accFG  = (double*)(w + 0);
  double* accCLS = (double*)(w + 256);
  double* accBOX = (double*)(w + 512);
  unsigned int* maxpg = (unsigned int*)(w + 1024);   // [B*G]

  k_init<<<1, 256, 0, stream>>>(accFG, maxpg, B * G);

  const int CH = 128;  // anchors per wave
  dim3 gB((R + 4 * CH - 1) / (4 * CH), B);
  k_maxpg<<<gB, 256, 0, stream>>>(anchors, gtb, maxpg, R, G, CH);

  dim3 gC((R + 511) / 512, B);
  k_fused<<<gC, 256, 0, stream>>>(anchors, gtb, gtl, deltas, logits, maxpg,
                                  accFG, accCLS, accBOX, R, G);

  k_final<<<1, 64, 0, stream>>>(accFG, accCLS, accBOX, out);
}